// Round 3
// baseline (538.262 us; speedup 1.0000x reference)
//
#include <hip/hip_runtime.h>
#include <hip/hip_runtime_api.h>

// Trilinear interpolation of 2M points into a 128x128x128x16 fp32 grid.
// Round-2 finding: random 64B gathers over the 134MB table saturate the
// memory system at ~3.5 TB/s regardless of per-wave MLP (VALUBusy 7.5%,
// occupancy 79%). Fix: spatial counting-sort of points into 32^3 buckets
// (4^3 voxels each; 8KB corner footprint per bucket) so gathers become
// L2-resident, then trilerp in sorted order writing to original slots.

#define DD 128
#define HH 128
#define WW 128
#define NBUCKET 32768   // 32^3

__device__ __forceinline__ int bucket_of(float px, float py, float pz) {
    int x0 = min(max((int)floorf(px * 20.0f), 0), DD - 1);
    int y0 = min(max((int)floorf(py * 20.0f), 0), HH - 1);
    int z0 = min(max((int)floorf(pz * 20.0f), 0), WW - 1);
    return (((x0 >> 2) << 5) + (y0 >> 2)) * 32 + (z0 >> 2);
}

__global__ __launch_bounds__(256) void hist_kernel(
    const float* __restrict__ points, unsigned int* __restrict__ hist, int n)
{
    int p = blockIdx.x * blockDim.x + threadIdx.x;
    if (p >= n) return;
    float px = points[3 * p + 0], py = points[3 * p + 1], pz = points[3 * p + 2];
    atomicAdd(&hist[bucket_of(px, py, pz)], 1u);
}

// Single-block exclusive scan over 32768 counters. 1024 threads x 32 each.
__global__ __launch_bounds__(1024) void scan_kernel(
    const unsigned int* __restrict__ hist, unsigned int* __restrict__ offsets)
{
    __shared__ unsigned int partial[1024];
    int t = threadIdx.x;
    unsigned int vals[32];
    unsigned int sum = 0;
    #pragma unroll
    for (int i = 0; i < 32; ++i) { vals[i] = hist[t * 32 + i]; sum += vals[i]; }
    partial[t] = sum;
    __syncthreads();
    for (int off = 1; off < 1024; off <<= 1) {
        unsigned int v = (t >= off) ? partial[t - off] : 0u;
        __syncthreads();
        partial[t] += v;
        __syncthreads();
    }
    unsigned int run = (t == 0) ? 0u : partial[t - 1];
    #pragma unroll
    for (int i = 0; i < 32; ++i) { offsets[t * 32 + i] = run; run += vals[i]; }
}

__global__ __launch_bounds__(256) void scatter_kernel(
    const float* __restrict__ points, unsigned int* __restrict__ offsets,
    float4* __restrict__ sorted, int n)
{
    int p = blockIdx.x * blockDim.x + threadIdx.x;
    if (p >= n) return;
    float px = points[3 * p + 0], py = points[3 * p + 1], pz = points[3 * p + 2];
    unsigned int pos = atomicAdd(&offsets[bucket_of(px, py, pz)], 1u);
    sorted[pos] = make_float4(px, py, pz, __int_as_float(p));
}

__device__ __forceinline__ float4 lerp4(float4 a, float4 b, float t) {
    return make_float4(fmaf(b.x - a.x, t, a.x),
                       fmaf(b.y - a.y, t, a.y),
                       fmaf(b.z - a.z, t, a.z),
                       fmaf(b.w - a.w, t, a.w));
}

// 4 lanes per point; lane handles one float4 of the 16 channels.
__global__ __launch_bounds__(256) void trilerp_sorted_kernel(
    const float4* __restrict__ sorted,
    const float4* __restrict__ values,
    float4* __restrict__ out,
    int n_points)
{
    int t = blockIdx.x * blockDim.x + threadIdx.x;
    int p = t >> 2;
    int c4 = t & 3;
    if (p >= n_points) return;

    float4 s = sorted[p];
    float x = s.x * 20.0f, y = s.y * 20.0f, z = s.z * 20.0f;
    int idx = __float_as_int(s.w);

    int x0 = min(max((int)floorf(x), 0), DD - 1);
    int y0 = min(max((int)floorf(y), 0), HH - 1);
    int z0 = min(max((int)floorf(z), 0), WW - 1);
    int x1 = min(x0 + 1, DD - 1);
    int y1 = min(y0 + 1, HH - 1);
    int z1 = min(z0 + 1, WW - 1);
    float xd = x - (float)x0;
    float yd = y - (float)y0;
    float zd = z - (float)z0;

    #define VIDX(xi, yi, zi) ((((((xi) << 7) + (yi)) << 7) + (zi)) * 4 + c4)
    float4 c000 = values[VIDX(x0, y0, z0)];
    float4 c001 = values[VIDX(x0, y0, z1)];
    float4 c010 = values[VIDX(x0, y1, z0)];
    float4 c011 = values[VIDX(x0, y1, z1)];
    float4 c100 = values[VIDX(x1, y0, z0)];
    float4 c101 = values[VIDX(x1, y0, z1)];
    float4 c110 = values[VIDX(x1, y1, z0)];
    float4 c111 = values[VIDX(x1, y1, z1)];
    #undef VIDX

    float4 c00 = lerp4(c000, c100, xd);
    float4 c01 = lerp4(c001, c101, xd);
    float4 c10 = lerp4(c010, c110, xd);
    float4 c11 = lerp4(c011, c111, xd);
    float4 c0 = lerp4(c00, c10, yd);
    float4 c1 = lerp4(c01, c11, yd);
    out[idx * 4 + c4] = lerp4(c0, c1, zd);
}

// Fallback (round-1 kernel): direct, unsorted.
__global__ __launch_bounds__(256) void trilerp_direct_kernel(
    const float* __restrict__ points,
    const float4* __restrict__ values,
    float4* __restrict__ out,
    int n_points)
{
    int t = blockIdx.x * blockDim.x + threadIdx.x;
    int p = t >> 2;
    int c4 = t & 3;
    if (p >= n_points) return;

    float x = points[p * 3 + 0] * 20.0f;
    float y = points[p * 3 + 1] * 20.0f;
    float z = points[p * 3 + 2] * 20.0f;
    int x0 = min(max((int)floorf(x), 0), DD - 1);
    int y0 = min(max((int)floorf(y), 0), HH - 1);
    int z0 = min(max((int)floorf(z), 0), WW - 1);
    int x1 = min(x0 + 1, DD - 1);
    int y1 = min(y0 + 1, HH - 1);
    int z1 = min(z0 + 1, WW - 1);
    float xd = x - (float)x0, yd = y - (float)y0, zd = z - (float)z0;

    #define VIDX(xi, yi, zi) ((((((xi) << 7) + (yi)) << 7) + (zi)) * 4 + c4)
    float4 c000 = values[VIDX(x0, y0, z0)];
    float4 c001 = values[VIDX(x0, y0, z1)];
    float4 c010 = values[VIDX(x0, y1, z0)];
    float4 c011 = values[VIDX(x0, y1, z1)];
    float4 c100 = values[VIDX(x1, y0, z0)];
    float4 c101 = values[VIDX(x1, y0, z1)];
    float4 c110 = values[VIDX(x1, y1, z0)];
    float4 c111 = values[VIDX(x1, y1, z1)];
    #undef VIDX

    float4 c00 = lerp4(c000, c100, xd);
    float4 c01 = lerp4(c001, c101, xd);
    float4 c10 = lerp4(c010, c110, xd);
    float4 c11 = lerp4(c011, c111, xd);
    float4 c0 = lerp4(c00, c10, yd);
    float4 c1 = lerp4(c01, c11, yd);
    out[t] = lerp4(c0, c1, zd);
}

extern "C" void kernel_launch(void* const* d_in, const int* in_sizes, int n_in,
                              void* d_out, int out_size, void* d_ws, size_t ws_size,
                              hipStream_t stream) {
    const float* points = (const float*)d_in[0];
    const float4* values = (const float4*)d_in[1];
    float4* out = (float4*)d_out;

    int n_points = in_sizes[0] / 3;
    size_t need = (size_t)NBUCKET * 8 + (size_t)n_points * 16;

    if (ws_size < need) {
        int total = n_points * 4;
        trilerp_direct_kernel<<<(total + 255) / 256, 256, 0, stream>>>(
            points, values, out, n_points);
        return;
    }

    unsigned int* hist = (unsigned int*)d_ws;                       // 128 KB
    unsigned int* offsets = hist + NBUCKET;                         // 128 KB
    float4* sorted = (float4*)((char*)d_ws + (size_t)NBUCKET * 8);  // 32 MB

    hipMemsetAsync(hist, 0, NBUCKET * sizeof(unsigned int), stream);

    int pblocks = (n_points + 255) / 256;
    hist_kernel<<<pblocks, 256, 0, stream>>>(points, hist, n_points);
    scan_kernel<<<1, 1024, 0, stream>>>(hist, offsets);
    scatter_kernel<<<pblocks, 256, 0, stream>>>(points, offsets, sorted, n_points);

    int total = n_points * 4;
    trilerp_sorted_kernel<<<(total + 255) / 256, 256, 0, stream>>>(
        sorted, values, out, n_points);
}

// Round 4
// 453.800 us; speedup vs baseline: 1.1861x; 1.1861x over previous
//
#include <hip/hip_runtime.h>
#include <hip/hip_runtime_api.h>

// Trilinear interpolation of 2M points into a 128x128x128x16 fp32 grid.
//
// Round-3 findings: scatter_kernel (returning atomics on 16-counters-per-line
// offsets + random 16B stores) cost 155us on its own; sorted trilerp <154us
// confirmed locality helps. Round-4 design:
//   Kernel A (bin):     rank = atomicAdd on 64B-PADDED counters, direct store
//                       to fixed-capacity bucket slots. One pass, no scan.
//   Kernel B (trilerp): one block per 4^3-voxel bucket; 8KB corner footprint
//                       is L1-resident; XCD-swizzled bucket assignment.
//   Kernel C (overflow): direct trilerp for the ~0-2000 points whose bucket
//                       exceeded capacity (Poisson lambda=61, cap>=76).

#define DD 128
#define HH 128
#define WW 128
#define NBUCKET 32768        // 32^3 buckets of 4^3 voxels
#define CNT_STRIDE 16        // pad counters to one per 64B line
#define OVF_CAP 16384

__device__ __forceinline__ int bucket_of(float px, float py, float pz) {
    int x0 = min(max((int)floorf(px * 20.0f), 0), DD - 1);
    int y0 = min(max((int)floorf(py * 20.0f), 0), HH - 1);
    int z0 = min(max((int)floorf(pz * 20.0f), 0), WW - 1);
    return (((x0 >> 2) << 5) + (y0 >> 2)) * 32 + (z0 >> 2);
}

__device__ __forceinline__ float4 lerp4(float4 a, float4 b, float t) {
    return make_float4(fmaf(b.x - a.x, t, a.x),
                       fmaf(b.y - a.y, t, a.y),
                       fmaf(b.z - a.z, t, a.z),
                       fmaf(b.w - a.w, t, a.w));
}

// Full trilinear interp of one point for channel-group c4; returns float4,
// writes to out[idx*4+c4].
__device__ __forceinline__ void interp_store(float4 s, const float4* __restrict__ values,
                                             float4* __restrict__ out, int c4) {
    float x = s.x * 20.0f, y = s.y * 20.0f, z = s.z * 20.0f;
    int idx = __float_as_int(s.w);

    int x0 = min(max((int)floorf(x), 0), DD - 1);
    int y0 = min(max((int)floorf(y), 0), HH - 1);
    int z0 = min(max((int)floorf(z), 0), WW - 1);
    int x1 = min(x0 + 1, DD - 1);
    int y1 = min(y0 + 1, HH - 1);
    int z1 = min(z0 + 1, WW - 1);
    float xd = x - (float)x0;
    float yd = y - (float)y0;
    float zd = z - (float)z0;

    #define VIDX(xi, yi, zi) ((((((xi) << 7) + (yi)) << 7) + (zi)) * 4 + c4)
    float4 c000 = values[VIDX(x0, y0, z0)];
    float4 c001 = values[VIDX(x0, y0, z1)];
    float4 c010 = values[VIDX(x0, y1, z0)];
    float4 c011 = values[VIDX(x0, y1, z1)];
    float4 c100 = values[VIDX(x1, y0, z0)];
    float4 c101 = values[VIDX(x1, y0, z1)];
    float4 c110 = values[VIDX(x1, y1, z0)];
    float4 c111 = values[VIDX(x1, y1, z1)];
    #undef VIDX

    float4 c00 = lerp4(c000, c100, xd);
    float4 c01 = lerp4(c001, c101, xd);
    float4 c10 = lerp4(c010, c110, xd);
    float4 c11 = lerp4(c011, c111, xd);
    float4 c0 = lerp4(c00, c10, yd);
    float4 c1 = lerp4(c01, c11, yd);
    out[idx * 4 + c4] = lerp4(c0, c1, zd);
}

// ---- Kernel A: fused binning (hist + scatter, no scan) ----
__global__ __launch_bounds__(256) void bin_kernel(
    const float* __restrict__ points,
    unsigned int* __restrict__ cnt,        // NBUCKET * CNT_STRIDE uints
    unsigned int* __restrict__ ovf_cnt,
    float4* __restrict__ ovf,
    float4* __restrict__ sorted,
    int n, int cap)
{
    int p = blockIdx.x * blockDim.x + threadIdx.x;
    if (p >= n) return;
    float px = points[3 * p + 0], py = points[3 * p + 1], pz = points[3 * p + 2];
    int b = bucket_of(px, py, pz);
    unsigned int r = atomicAdd(&cnt[b * CNT_STRIDE], 1u);
    float4 v = make_float4(px, py, pz, __int_as_float(p));
    if (r < (unsigned int)cap) {
        sorted[(size_t)b * cap + r] = v;
    } else {
        unsigned int o = atomicAdd(ovf_cnt, 1u);
        if (o < OVF_CAP) ovf[o] = v;
    }
}

// ---- Kernel B: one block per bucket; 4 lanes per point ----
__global__ __launch_bounds__(256) void trilerp_bucket_kernel(
    const float4* __restrict__ sorted,
    const unsigned int* __restrict__ cnt,
    const float4* __restrict__ values,
    float4* __restrict__ out,
    int cap)
{
    int blk = blockIdx.x;
    // XCD swizzle: give each XCD (blk&7) a contiguous bucket range.
    int b = ((blk & 7) << 12) + (blk >> 3);
    unsigned int n = min(cnt[b * CNT_STRIDE], (unsigned int)cap);
    int c4 = threadIdx.x & 3;
    const float4* base = sorted + (size_t)b * cap;
    for (unsigned int i = threadIdx.x >> 2; i < n; i += 64) {
        interp_store(base[i], values, out, c4);
    }
}

// ---- Kernel C: overflow cleanup (direct) ----
__global__ __launch_bounds__(256) void trilerp_ovf_kernel(
    const float4* __restrict__ ovf,
    const unsigned int* __restrict__ ovf_cnt,
    const float4* __restrict__ values,
    float4* __restrict__ out)
{
    unsigned int n = min(*ovf_cnt, (unsigned int)OVF_CAP);
    int t = blockIdx.x * blockDim.x + threadIdx.x;
    unsigned int p = (unsigned int)(t >> 2);
    if (p >= n) return;
    interp_store(ovf[p], values, out, t & 3);
}

// ---- Fallback: direct, unsorted (round-1 kernel, 253us known-good) ----
__global__ __launch_bounds__(256) void trilerp_direct_kernel(
    const float* __restrict__ points,
    const float4* __restrict__ values,
    float4* __restrict__ out,
    int n_points)
{
    int t = blockIdx.x * blockDim.x + threadIdx.x;
    int p = t >> 2;
    int c4 = t & 3;
    if (p >= n_points) return;
    float4 s = make_float4(points[p * 3], points[p * 3 + 1], points[p * 3 + 2],
                           __int_as_float(p));
    interp_store(s, values, out, c4);
}

extern "C" void kernel_launch(void* const* d_in, const int* in_sizes, int n_in,
                              void* d_out, int out_size, void* d_ws, size_t ws_size,
                              hipStream_t stream) {
    const float* points = (const float*)d_in[0];
    const float4* values = (const float4*)d_in[1];
    float4* out = (float4*)d_out;
    int n_points = in_sizes[0] / 3;

    // Workspace layout:
    //   cnt:     NBUCKET * CNT_STRIDE * 4 B = 2 MB      @ 0
    //   ovf_cnt: 64 B                                   @ 2 MB
    //   ovf:     OVF_CAP * 16 B = 256 KB                @ 2 MB + 4 KB
    //   sorted:  NBUCKET * cap * 16 B                   @ 2.5 MB
    size_t cnt_bytes = (size_t)NBUCKET * CNT_STRIDE * 4;
    size_t sorted_off = cnt_bytes + (512u << 10);
    long long avail = (long long)ws_size - (long long)sorted_off;
    int cap = (int)(avail / ((long long)NBUCKET * 16));
    if (cap > 96) cap = 96;

    if (cap < 76) {
        // Not enough workspace for the binned path.
        int total = n_points * 4;
        trilerp_direct_kernel<<<(total + 255) / 256, 256, 0, stream>>>(
            points, values, out, n_points);
        return;
    }

    unsigned int* cnt = (unsigned int*)d_ws;
    unsigned int* ovf_cnt = (unsigned int*)((char*)d_ws + cnt_bytes);
    float4* ovf = (float4*)((char*)d_ws + cnt_bytes + 4096);
    float4* sorted = (float4*)((char*)d_ws + sorted_off);

    hipMemsetAsync(cnt, 0, cnt_bytes, stream);
    hipMemsetAsync(ovf_cnt, 0, 64, stream);

    int pblocks = (n_points + 255) / 256;
    bin_kernel<<<pblocks, 256, 0, stream>>>(points, cnt, ovf_cnt, ovf, sorted,
                                            n_points, cap);
    trilerp_bucket_kernel<<<NBUCKET, 256, 0, stream>>>(sorted, cnt, values, out, cap);
    trilerp_ovf_kernel<<<(OVF_CAP * 4) / 256, 256, 0, stream>>>(ovf, ovf_cnt, values, out);
}